// Round 5
// baseline (387.945 us; speedup 1.0000x reference)
//
#include <hip/hip_runtime.h>
#include <hip/hip_bf16.h>
#include <cstdint>
#include <cstddef>

// ---------------- types ----------------
typedef __bf16 bf16;
typedef __bf16 bf16x2 __attribute__((ext_vector_type(2)));
typedef __bf16 bf16x4 __attribute__((ext_vector_type(4)));
typedef __bf16 bf16x8 __attribute__((ext_vector_type(8)));
typedef float  floatx4 __attribute__((ext_vector_type(4)));

// problem constants
#define BB 8
#define SS 1024
#define DD 1024
#define RR 16
#define CHK 64
#define NCH 16

// params buffer layout (floats)
#define PP_ALPHA 0
#define PP_GAMMA 16
#define PP_GP    32           // 16*72: gamma^0..gamma^71 per r
#define PP_KKER  (32 + 16*72)
#define PP_FLOATS 2048

__device__ __forceinline__ float sigmoidf_(float x) { return 1.0f / (1.0f + __expf(-x)); }

__device__ __forceinline__ float gelu_f(float x) {
    float u = 0.7978845608028654f * (x + 0.044715f * x * x * x);
    float t = 1.0f - 2.0f / (__expf(2.0f * u) + 1.0f);
    return 0.5f * x * (1.0f + t);
}

__device__ __forceinline__ void g2l16(const bf16* g, bf16* l) {
    __builtin_amdgcn_global_load_lds(
        (const __attribute__((address_space(1))) void*)g,
        (__attribute__((address_space(3))) void*)l, 16, 0, 0);
}

// ---------------- fused prologue: rmsnorm1 + params + uvt + cvt + trcvt -----
// [0,8192): rmsnorm1 rows | +0: params | +[1,33): uvt | +[33,1057): cvt Wp
// +[1057,2081): trcvt W1 | +[2081,3105): trcvt W2
__global__ __launch_bounds__(256) void prep_kernel(
    const float* __restrict__ h, const float* __restrict__ norm1_w,
    const float* __restrict__ decay_logit, const float* __restrict__ alpha_logit,
    const float* __restrict__ gate_logit,  const float* __restrict__ kbase,
    const float* __restrict__ u, const float* __restrict__ v,
    const float* __restrict__ proj_w, const float* __restrict__ mlp_w1,
    const float* __restrict__ mlp_w2,
    float* __restrict__ pp, bf16* __restrict__ hn, bf16* __restrict__ Ut,
    bf16* __restrict__ Wp, bf16* __restrict__ W1t, bf16* __restrict__ W2t) {
    __shared__ float tl[64][69];
    __shared__ float red[4];
    int t = threadIdx.x;
    int bid = blockIdx.x;
    if (bid < 8192) {
        size_t row = bid;
        float4 hv = ((const float4*)(h + row * DD))[t];
        float ss = hv.x*hv.x + hv.y*hv.y + hv.z*hv.z + hv.w*hv.w;
        for (int m = 32; m; m >>= 1) ss += __shfl_xor(ss, m);
        if ((t & 63) == 0) red[t >> 6] = ss;
        __syncthreads();
        float tot = red[0] + red[1] + red[2] + red[3];
        float rinv = rsqrtf(tot * (1.0f / 1024.0f) + 1e-6f);
        float4 wv = ((const float4*)norm1_w)[t];
        bf16x4 o = { (bf16)(hv.x * rinv * wv.x), (bf16)(hv.y * rinv * wv.y),
                     (bf16)(hv.z * rinv * wv.z), (bf16)(hv.w * rinv * wv.w) };
        ((bf16x4*)(hn + row * DD))[t] = o;
        return;
    }
    int b2 = bid - 8192;
    if (b2 == 0) {
        if (t < 16) {
            pp[PP_ALPHA + t] = sigmoidf_(alpha_logit[t]);
            float g = sigmoidf_(decay_logit[t]);
            g = fminf(fmaxf(g, 0.15f), 1.0f);
            pp[PP_GAMMA + t] = g;
            float acc = 1.0f;
            for (int p = 0; p < 72; ++p) { pp[PP_GP + t * 72 + p] = acc; acc *= g; }
        }
        if (t >= 16 && t < 20) {
            float gate = sigmoidf_(gate_logit[0]);
            pp[PP_KKER + (t - 16)] = gate * kbase[t - 16];
        }
        return;
    }
    if (b2 < 33) {
        int c = b2 - 1;
        const float* src = (c < 16) ? u : v;
        int cc = c & 15;
        for (int d = t; d < 1024; d += 256)
            Ut[c * 1024 + d] = (bf16)src[d * 16 + cc];
        return;
    }
    if (b2 < 1057) {
        int i = (b2 - 33) * 256 + t;
        float4 w = ((const float4*)proj_w)[i];
        bf16x4 o = { (bf16)w.x, (bf16)w.y, (bf16)w.z, (bf16)w.w };
        ((bf16x4*)Wp)[i] = o;
        return;
    }
    const float* in; bf16* outp; int K, N, tb;
    if (b2 < 2081) { in = mlp_w1; outp = W1t; K = 1024; N = 4096; tb = b2 - 1057; }
    else           { in = mlp_w2; outp = W2t; K = 4096; N = 1024; tb = b2 - 2081; }
    int nx = N >> 6;
    int x0 = (tb % nx) * 64, y0 = (tb / nx) * 64;
    int tx = t & 15, ty = t >> 4;
    #pragma unroll
    for (int i = 0; i < 4; ++i) {
        float4 w = *(const float4*)(in + (size_t)(y0 + ty + i * 16) * N + x0 + tx * 4);
        tl[ty + i * 16][tx * 4 + 0] = w.x; tl[ty + i * 16][tx * 4 + 1] = w.y;
        tl[ty + i * 16][tx * 4 + 2] = w.z; tl[ty + i * 16][tx * 4 + 3] = w.w;
    }
    __syncthreads();
    #pragma unroll
    for (int i = 0; i < 4; ++i) {
        int nl = ty + i * 16;
        bf16x4 o = { (bf16)tl[tx * 4 + 0][nl], (bf16)tl[tx * 4 + 1][nl],
                     (bf16)tl[tx * 4 + 2][nl], (bf16)tl[tx * 4 + 3][nl] };
        *(bf16x4*)(outp + (size_t)(x0 + nl) * K + y0 + tx * 4) = o;
    }
}

// ---------------- rmsnorm2 (bf16 in, bf16 out) ----------------
__global__ __launch_bounds__(256) void rms2b_kernel(
    const bf16* __restrict__ x, const float* __restrict__ nw, bf16* __restrict__ y) {
    __shared__ float red[4];
    int t = threadIdx.x;
    size_t row = blockIdx.x;
    bf16x4 hv = ((const bf16x4*)(x + row * DD))[t];
    float x0 = (float)hv[0], x1 = (float)hv[1], x2 = (float)hv[2], x3 = (float)hv[3];
    float ss = x0*x0 + x1*x1 + x2*x2 + x3*x3;
    for (int m = 32; m; m >>= 1) ss += __shfl_xor(ss, m);
    if ((t & 63) == 0) red[t >> 6] = ss;
    __syncthreads();
    float tot = red[0] + red[1] + red[2] + red[3];
    float rinv = rsqrtf(tot * (1.0f / 1024.0f) + 1e-6f);
    float4 wv = ((const float4*)nw)[t];
    bf16x4 o = { (bf16)(x0 * rinv * wv.x), (bf16)(x1 * rinv * wv.y),
                 (bf16)(x2 * rinv * wv.z), (bf16)(x3 * rinv * wv.w) };
    ((bf16x4*)(y + row * DD))[t] = o;
}

// ---------------- qk projection + l2norm via MFMA, 32-row tiles, BK=128 -----
__global__ __launch_bounds__(256) void qk_kernel(
    const bf16* __restrict__ hn, const bf16* __restrict__ Ut,
    const float* __restrict__ pp, float* __restrict__ qa, float* __restrict__ kk) {
    __shared__ __attribute__((aligned(16))) bf16 As[32 * 128];
    __shared__ __attribute__((aligned(16))) bf16 Bs[32 * 128];
    int tid = threadIdx.x, lane = tid & 63, wid = tid >> 6;
    int quad = lane >> 4, l16 = lane & 15;
    int m0 = blockIdx.x * 32;
    int mt = wid >> 1, nt = wid & 1;
    const bf16* Ap[2]; const bf16* Bp[2]; int lo[2];
    #pragma unroll
    for (int j = 0; j < 2; ++j) {
        int s = j * 256 + tid;
        int row = s >> 4, cc = s & 15;
        int gc = cc ^ (row & 15);
        Ap[j] = hn + (size_t)(m0 + row) * DD + gc * 8;
        Bp[j] = Ut + (size_t)row * DD + gc * 8;
        lo[j] = s * 8;
    }
    floatx4 acc = {};
    for (int kt = 0; kt < 1024; kt += 128) {
        #pragma unroll
        for (int j = 0; j < 2; ++j) {
            g2l16(Ap[j] + kt, As + lo[j]);
            g2l16(Bp[j] + kt, Bs + lo[j]);
        }
        __syncthreads();
        #pragma unroll
        for (int ks = 0; ks < 4; ++ks) {
            int arow = mt * 16 + l16;
            int acc_ = (ks * 4 + quad) ^ (arow & 15);
            bf16x8 af = *(const bf16x8*)(As + arow * 128 + acc_ * 8);
            int brow = nt * 16 + l16;
            int bcc = (ks * 4 + quad) ^ (brow & 15);
            bf16x8 bfr = *(const bf16x8*)(Bs + brow * 128 + bcc * 8);
            acc = __builtin_amdgcn_mfma_f32_16x16x32_bf16(af, bfr, acc, 0, 0, 0);
        }
        __syncthreads();
    }
    float alf = pp[PP_ALPHA + l16];
    float s2[4];
    #pragma unroll
    for (int r = 0; r < 4; ++r) s2[r] = acc[r] * acc[r];
    #pragma unroll
    for (int m = 1; m <= 8; m <<= 1)
        #pragma unroll
        for (int r = 0; r < 4; ++r) s2[r] += __shfl_xor(s2[r], m);
    #pragma unroll
    for (int r = 0; r < 4; ++r) {
        size_t row = m0 + mt * 16 + quad * 4 + r;
        float den = fmaxf(sqrtf(s2[r]), 1e-8f);
        float nvl = acc[r] / den;
        if (nt == 0) qa[row * RR + l16] = nvl * alf;
        else         kk[row * RR + l16] = nvl;
    }
}

// ---------------- phase A: per-chunk KV increments ----------------
__global__ __launch_bounds__(256) void incr_kernel(
    const bf16* __restrict__ hn, const float* __restrict__ kk,
    const float* __restrict__ pp, float* __restrict__ Inc) {
    __shared__ __attribute__((aligned(16))) float wjr[64][16];
    int t = threadIdx.x;
    int bc = blockIdx.x;
    int d0 = blockIdx.y * 512 + t * 2;
    size_t row0 = (size_t)bc * 64;
    for (int idx = t; idx < 1024; idx += 256) {
        int j = idx >> 4, r = idx & 15;
        wjr[j][r] = kk[(row0 + j) * RR + r] * pp[PP_GP + r * 72 + (63 - j)];
    }
    __syncthreads();
    float acc0[16] = {}, acc1[16] = {};
    for (int j = 0; j < 64; ++j) {
        bf16x2 hv = *(const bf16x2*)(hn + (row0 + j) * DD + d0);
        float x0 = (float)hv[0], x1 = (float)hv[1];
        const float4* w4 = (const float4*)wjr[j];
        #pragma unroll
        for (int g = 0; g < 4; ++g) {
            float4 w = w4[g];
            acc0[g*4+0] += w.x * x0; acc0[g*4+1] += w.y * x0;
            acc0[g*4+2] += w.z * x0; acc0[g*4+3] += w.w * x0;
            acc1[g*4+0] += w.x * x1; acc1[g*4+1] += w.y * x1;
            acc1[g*4+2] += w.z * x1; acc1[g*4+3] += w.w * x1;
        }
    }
    float* outp = Inc + (size_t)bc * 16 * 1024 + d0;
    #pragma unroll
    for (int r = 0; r < 16; ++r) {
        float2 o = { acc0[r], acc1[r] };
        *(float2*)&outp[r * 1024] = o;
    }
}

// ---------------- phase B: sequential chunk-state scan (bf16 out) -----------
__global__ __launch_bounds__(256) void scan_kernel(
    const float* __restrict__ Inc, const float* __restrict__ pp,
    bf16* __restrict__ Sprevb) {
    int gid = blockIdx.x * 256 + threadIdx.x;
    int b = gid >> 14, rd = gid & 16383;
    int r = rd >> 10;
    float gd = pp[PP_GP + r * 72 + 64];
    float s = 0.0f;
    for (int c = 0; c < 16; ++c) {
        size_t idx = ((size_t)(b * 16 + c) << 14) + rd;
        Sprevb[idx] = (bf16)s;
        s = s * gd + Inc[idx];
    }
}

// ---------------- phase C via MFMA: M(64x96) @ X(96x1024-slice) -------------
#define XK 104
__global__ __launch_bounds__(256, 2) void phasec_kernel(
    const bf16* __restrict__ hn, const float* __restrict__ qa, const float* __restrict__ kk,
    const bf16* __restrict__ Sprevb, const float* __restrict__ pp,
    bf16* __restrict__ outpre) {
    __shared__ __attribute__((aligned(16))) bf16 Xt[128][XK];
    __shared__ __attribute__((aligned(16))) bf16 Mb[64][XK];
    __shared__ __attribute__((aligned(16))) float qa_s[64][16];
    __shared__ __attribute__((aligned(16))) float kk_s[64][16];
    __shared__ __attribute__((aligned(16))) float gpt[65][16];
    __shared__ float kks[4];
    int t = threadIdx.x;
    int bc = blockIdx.x;
    int c = bc & 15;
    size_t row0 = (size_t)bc * 64;
    for (int idx = t; idx < 1024; idx += 256) {
        int j = idx >> 4, r = idx & 15;
        qa_s[j][r] = qa[(row0 + j) * RR + r];
        kk_s[j][r] = kk[(row0 + j) * RR + r];
    }
    for (int idx = t; idx < 16 * 65; idx += 256) {
        int p = idx >> 4, r = idx & 15;
        gpt[p][r] = pp[PP_GP + r * 72 + p];
    }
    if (t < 4) kks[t] = pp[PP_KKER + t];
    __syncthreads();
    for (int idx = t; idx < 64 * 96; idx += 256) {
        int ii = idx / 96, jj = idx - ii * 96;
        float val = 0.0f;
        if (jj < 64) {
            if (jj <= ii) {
                const float4* qa4 = (const float4*)qa_s[ii];
                const float4* kk4 = (const float4*)kk_s[jj];
                const float4* gp4 = (const float4*)gpt[ii - jj];
                float s = 0.0f;
                #pragma unroll
                for (int x = 0; x < 4; ++x) {
                    float4 qv = qa4[x], kv = kk4[x], gv = gp4[x];
                    s += qv.x*kv.x*gv.x + qv.y*kv.y*gv.y + qv.z*kv.z*gv.z + qv.w*kv.w*gv.w;
                }
                val = s;
                if (ii - jj <= 3) val += kks[ii - jj];
            }
        } else if (jj < 80) {
            int r = jj - 64;
            val = qa_s[ii][r] * gpt[ii + 1][r];
        } else if (jj < 83) {
            int p = jj - 80;
            if (ii <= p) val = kks[ii + 3 - p];
        }
        Mb[ii][jj] = (bf16)val;
    }
    int lane = t & 63, w = t >> 6, quad = lane >> 4, l16 = lane & 15;
    for (int it = 0; it < 2; ++it) {
        int dt = blockIdx.y * 256 + it * 128;
        __syncthreads();
        for (int idx = t; idx < 64 * 32; idx += 256) {
            int j = idx >> 5, ch = idx & 31;
            bf16x4 hv = *(const bf16x4*)(hn + (row0 + j) * DD + dt + ch * 4);
            #pragma unroll
            for (int ee = 0; ee < 4; ++ee) {
                int e = (ee + t) & 3;
                Xt[ch * 4 + e][j] = hv[e];
            }
        }
        for (int idx = t; idx < 16 * 128; idx += 256) {
            int r = idx >> 7, dd = idx & 127;
            Xt[dd][64 + r] = Sprevb[((size_t)bc << 14) + r * 1024 + dt + dd];
        }
        for (int idx = t; idx < 128 * 16; idx += 256) {
            int dd = idx >> 4, p = idx & 15;
            bf16 val = (bf16)0.0f;
            if (p < 3 && c > 0) val = hn[(row0 - 3 + p) * DD + dt + dd];
            Xt[dd][80 + p] = val;
        }
        __syncthreads();
        floatx4 acc[8] = {};
        #pragma unroll
        for (int ks = 0; ks < 3; ++ks) {
            bf16x8 af = *(const bf16x8*)(&Mb[w * 16 + l16][ks * 32 + quad * 8]);
            #pragma unroll
            for (int tn = 0; tn < 8; ++tn) {
                bf16x8 bfr = *(const bf16x8*)(&Xt[tn * 16 + l16][ks * 32 + quad * 8]);
                acc[tn] = __builtin_amdgcn_mfma_f32_16x16x32_bf16(af, bfr, acc[tn], 0, 0, 0);
            }
        }
        #pragma unroll
        for (int tn = 0; tn < 8; ++tn) {
            #pragma unroll
            for (int r = 0; r < 4; ++r) {
                size_t ii = w * 16 + quad * 4 + r;
                outpre[(row0 + ii) * DD + dt + tn * 16 + l16] = (bf16)acc[tn][r];
            }
        }
    }
}

// ---------------- MFMA GEMM, templated, XOR-swizzled LDS, XCD cohorts -------
// EPI 0: outb = (bf16)(acc + bias + residf)   [proj -> h2b]
// EPI 1: outb = gelu(acc + bias), LDS-staged coalesced stores [mlp1 -> hidden]
// EPI 2: outf = acc + bias + (float)residb    [mlp2 -> d_out]
template <int EPI, int BK>
__global__ __launch_bounds__(256, 2) void gemm_bt_kernel(
    const bf16* __restrict__ A, const bf16* __restrict__ Bt,
    const float* __restrict__ bias, const float* __restrict__ residf,
    const bf16* __restrict__ residb, float* __restrict__ outf,
    bf16* __restrict__ outb, int K, int N) {
    constexpr int CH = BK / 8;
    constexpr int PT = 128 * CH / 256;
    __shared__ __attribute__((aligned(16))) bf16 smem[128 * BK * 2];
    bf16* As = smem;
    bf16* Bs = smem + 128 * BK;
    int tid = threadIdx.x, lane = tid & 63, wid = tid >> 6;
    int quad = lane >> 4, l16 = lane & 15;
    int lb = blockIdx.y * gridDim.x + blockIdx.x;
    int xcd = lb & 7, q = lb >> 3;
    int m0 = (xcd * 8 + (q & 7)) * 128;
    int n0 = (q >> 3) * 128;
    int wm = (wid >> 1) * 64, wn = (wid & 1) * 64;
    const bf16* Ap[PT]; const bf16* Bp[PT]; int lo[PT];
    #pragma unroll
    for (int j = 0; j < PT; ++j) {
        int s = j * 256 + tid;
        int row = s / CH, cc = s % CH;
        int gc = cc ^ (row & (CH - 1));
        Ap[j] = A  + (size_t)(m0 + row) * K + gc * 8;
        Bp[j] = Bt + (size_t)(n0 + row) * K + gc * 8;
        lo[j] = s * 8;
    }
    floatx4 acc[4][4] = {};
    for (int kt = 0; kt < K; kt += BK) {
        #pragma unroll
        for (int j = 0; j < PT; ++j) {
            g2l16(Ap[j] + kt, As + lo[j]);
            g2l16(Bp[j] + kt, Bs + lo[j]);
        }
        __syncthreads();
        #pragma unroll
        for (int ks = 0; ks < BK / 32; ++ks) {
            bf16x8 af[4], bfr[4];
            #pragma unroll
            for (int tm = 0; tm < 4; ++tm) {
                int row = wm + tm * 16 + l16;
                int cc = (ks * 4 + quad) ^ (row & (CH - 1));
                af[tm] = *(const bf16x8*)(As + row * BK + cc * 8);
            }
            #pragma unroll
            for (int tn = 0; tn < 4; ++tn) {
                int row = wn + tn * 16 + l16;
                int cc = (ks * 4 + quad) ^ (row & (CH - 1));
                bfr[tn] = *(const bf16x8*)(Bs + row * BK + cc * 8);
            }
            #pragma unroll
            for (int tm = 0; tm < 4; ++tm)
                #pragma unroll
                for (int tn = 0; tn < 4; ++tn)
                    acc[tm][tn] = __builtin_amdgcn_mfma_f32_16x16x32_bf16(
                        af[tm], bfr[tn], acc[tm][tn], 0, 0, 0);
        }
        __syncthreads();
    }
    if (EPI == 1) {
        // staged coalesced bf16 stores, 64-row half-tiles, reusing smem
        bf16 (*Cs)[136] = (bf16 (*)[136])smem;
        #pragma unroll
        for (int p = 0; p < 2; ++p) {
            if ((wid >> 1) == p) {
                #pragma unroll
                for (int tn = 0; tn < 4; ++tn) {
                    int cl = wn + tn * 16 + l16;
                    float bs = bias[n0 + cl];
                    #pragma unroll
                    for (int tm = 0; tm < 4; ++tm)
                        #pragma unroll
                        for (int r = 0; r < 4; ++r)
                            Cs[tm * 16 + quad * 4 + r][cl] =
                                (bf16)gelu_f(acc[tm][tn][r] + bs);
                }
            }
            __syncthreads();
            int row = tid >> 2, cg = (tid & 3) * 32;
            const bf16* src = &Cs[row][cg];
            bf16* dst = outb + (size_t)(m0 + p * 64 + row) * N + n0 + cg;
            #pragma unroll
            for (int x = 0; x < 4; ++x)
                *(bf16x8*)(dst + x * 8) = *(const bf16x8*)(src + x * 8);
            __syncthreads();
        }
    } else {
        #pragma unroll
        for (int tn = 0; tn < 4; ++tn) {
            int gn = n0 + wn + tn * 16 + l16;
            float bs = bias[gn];
            #pragma unroll
            for (int tm = 0; tm < 4; ++tm) {
                #pragma unroll
                for (int r = 0; r < 4; ++r) {
                    size_t gm = (size_t)m0 + wm + tm * 16 + quad * 4 + r;
                    float v = acc[tm][tn][r] + bs;
                    if (EPI == 0) {
                        v += residf[gm * N + gn];
                        outb[gm * N + gn] = (bf16)v;
                    } else {
                        v += (float)residb[gm * N + gn];
                        outf[gm * N + gn] = v;
                    }
                }
            }
        }
    }
}

// ---------------- launch ----------------
extern "C" void kernel_launch(void* const* d_in, const int* in_sizes, int n_in,
                              void* d_out, int out_size, void* d_ws, size_t ws_size,
                              hipStream_t stream) {
    const float* h           = (const float*)d_in[0];
    const float* u           = (const float*)d_in[1];
    const float* v           = (const float*)d_in[2];
    const float* decay_logit = (const float*)d_in[3];
    const float* alpha_logit = (const float*)d_in[4];
    const float* gate_logit  = (const float*)d_in[5];
    const float* kbase       = (const float*)d_in[6];
    const float* proj_w      = (const float*)d_in[7];
    const float* proj_b      = (const float*)d_in[8];
    const float* norm1_w     = (const float*)d_in[9];
    const float* norm2_w     = (const float*)d_in[10];
    const float* mlp_w1      = (const float*)d_in[11];
    const float* mlp_b1      = (const float*)d_in[12];
    const float* mlp_w2      = (const float*)d_in[13];
    const float* mlp_b2      = (const float*)d_in[14];
    float* out = (float*)d_out;

    char* wsb = (char*)d_ws;
    size_t off = 0;
    auto alloc = [&](size_t bytes) -> void* {
        void* p = wsb + off;
        off += (bytes + 255) & ~(size_t)255;
        return p;
    };
    float* pp     = (float*)alloc(PP_FLOATS * 4);
    bf16*  Ut     = (bf16*) alloc((size_t)32 * 1024 * 2);
    bf16*  hn     = (bf16*) alloc((size_t)8192 * 1024 * 2);
    float* qa     = (float*)alloc((size_t)8192 * 16 * 4);
    float* kk     = (float*)alloc((size_t)8192 * 16 * 4);
    float* Inc    = (float*)alloc((size_t)128 * 16 * 1024 * 4);
    bf16*  Sprevb = (bf16*) alloc((size_t)128 * 16 * 1024 * 2);
    bf16*  outpre = (bf16*) alloc((size_t)8192 * 1024 * 2);
    bf16*  h2b    = (bf16*) alloc((size_t)8192 * 1024 * 2);
    bf16*  hidden = (bf16*) alloc((size_t)8192 * 4096 * 2);
    bf16*  Wp     = (bf16*) alloc((size_t)1024 * 1024 * 2);
    bf16*  W1t    = (bf16*) alloc((size_t)4096 * 1024 * 2);
    bf16*  W2t    = (bf16*) alloc((size_t)1024 * 4096 * 2);
    bf16*  hn2 = hn;   // hn dead after phasec

    prep_kernel<<<8192 + 3105, 256, 0, stream>>>(
        h, norm1_w, decay_logit, alpha_logit, gate_logit, kbase,
        u, v, proj_w, mlp_w1, mlp_w2, pp, hn, Ut, Wp, W1t, W2t);
    qk_kernel<<<256, 256, 0, stream>>>(hn, Ut, pp, qa, kk);
    incr_kernel<<<dim3(128, 2), 256, 0, stream>>>(hn, kk, pp, Inc);
    scan_kernel<<<512, 256, 0, stream>>>(Inc, pp, Sprevb);
    phasec_kernel<<<dim3(128, 4), 256, 0, stream>>>(hn, qa, kk, Sprevb, pp, outpre);
    gemm_bt_kernel<0, 128><<<dim3(8, 64), 256, 0, stream>>>(
        outpre, Wp, proj_b, h, nullptr, nullptr, h2b, 1024, 1024);
    rms2b_kernel<<<8192, 256, 0, stream>>>(h2b, norm2_w, hn2);
    gemm_bt_kernel<1, 64><<<dim3(32, 64), 256, 0, stream>>>(
        hn2, W1t, mlp_b1, nullptr, nullptr, nullptr, hidden, 1024, 4096);
    gemm_bt_kernel<2, 128><<<dim3(8, 64), 256, 0, stream>>>(
        hidden, W2t, mlp_b2, nullptr, h2b, out, nullptr, 4096, 1024);
}

// Round 6
// 369.843 us; speedup vs baseline: 1.0489x; 1.0489x over previous
//
#include <hip/hip_runtime.h>
#include <hip/hip_bf16.h>
#include <cstdint>
#include <cstddef>

// ---------------- types ----------------
typedef __bf16 bf16;
typedef __bf16 bf16x2 __attribute__((ext_vector_type(2)));
typedef __bf16 bf16x4 __attribute__((ext_vector_type(4)));
typedef __bf16 bf16x8 __attribute__((ext_vector_type(8)));
typedef float  floatx4 __attribute__((ext_vector_type(4)));

// problem constants
#define BB 8
#define SS 1024
#define DD 1024
#define RR 16
#define CHK 64
#define NCH 16

// params buffer layout (floats)
#define PP_ALPHA 0
#define PP_GAMMA 16
#define PP_GP    32           // 16*72: gamma^0..gamma^71 per r
#define PP_KKER  (32 + 16*72)
#define PP_FLOATS 2048

__device__ __forceinline__ float sigmoidf_(float x) { return 1.0f / (1.0f + __expf(-x)); }

__device__ __forceinline__ float gelu_f(float x) {
    float u = 0.7978845608028654f * (x + 0.044715f * x * x * x);
    float t = 1.0f - 2.0f / (__expf(2.0f * u) + 1.0f);
    return 0.5f * x * (1.0f + t);
}

__device__ __forceinline__ void g2l16(const bf16* g, bf16* l) {
    __builtin_amdgcn_global_load_lds(
        (const __attribute__((address_space(1))) void*)g,
        (__attribute__((address_space(3))) void*)l, 16, 0, 0);
}

// ---------------- fused prologue: rmsnorm1 + params + uvt + cvt + trcvt -----
// [0,8192): rmsnorm1 rows | +0: params | +[1,33): uvt | +[33,1057): cvt Wp
// +[1057,2081): trcvt W1 | +[2081,3105): trcvt W2
__global__ __launch_bounds__(256) void prep_kernel(
    const float* __restrict__ h, const float* __restrict__ norm1_w,
    const float* __restrict__ decay_logit, const float* __restrict__ alpha_logit,
    const float* __restrict__ gate_logit,  const float* __restrict__ kbase,
    const float* __restrict__ u, const float* __restrict__ v,
    const float* __restrict__ proj_w, const float* __restrict__ mlp_w1,
    const float* __restrict__ mlp_w2,
    float* __restrict__ pp, bf16* __restrict__ hn, bf16* __restrict__ Ut,
    bf16* __restrict__ Wp, bf16* __restrict__ W1t, bf16* __restrict__ W2t) {
    __shared__ float tl[64][69];
    __shared__ float red[4];
    int t = threadIdx.x;
    int bid = blockIdx.x;
    if (bid < 8192) {
        size_t row = bid;
        float4 hv = ((const float4*)(h + row * DD))[t];
        float ss = hv.x*hv.x + hv.y*hv.y + hv.z*hv.z + hv.w*hv.w;
        for (int m = 32; m; m >>= 1) ss += __shfl_xor(ss, m);
        if ((t & 63) == 0) red[t >> 6] = ss;
        __syncthreads();
        float tot = red[0] + red[1] + red[2] + red[3];
        float rinv = rsqrtf(tot * (1.0f / 1024.0f) + 1e-6f);
        float4 wv = ((const float4*)norm1_w)[t];
        bf16x4 o = { (bf16)(hv.x * rinv * wv.x), (bf16)(hv.y * rinv * wv.y),
                     (bf16)(hv.z * rinv * wv.z), (bf16)(hv.w * rinv * wv.w) };
        ((bf16x4*)(hn + row * DD))[t] = o;
        return;
    }
    int b2 = bid - 8192;
    if (b2 == 0) {
        if (t < 16) {
            pp[PP_ALPHA + t] = sigmoidf_(alpha_logit[t]);
            float g = sigmoidf_(decay_logit[t]);
            g = fminf(fmaxf(g, 0.15f), 1.0f);
            pp[PP_GAMMA + t] = g;
            float acc = 1.0f;
            for (int p = 0; p < 72; ++p) { pp[PP_GP + t * 72 + p] = acc; acc *= g; }
        }
        if (t >= 16 && t < 20) {
            float gate = sigmoidf_(gate_logit[0]);
            pp[PP_KKER + (t - 16)] = gate * kbase[t - 16];
        }
        return;
    }
    if (b2 < 33) {
        int c = b2 - 1;
        const float* src = (c < 16) ? u : v;
        int cc = c & 15;
        for (int d = t; d < 1024; d += 256)
            Ut[c * 1024 + d] = (bf16)src[d * 16 + cc];
        return;
    }
    if (b2 < 1057) {
        int i = (b2 - 33) * 256 + t;
        float4 w = ((const float4*)proj_w)[i];
        bf16x4 o = { (bf16)w.x, (bf16)w.y, (bf16)w.z, (bf16)w.w };
        ((bf16x4*)Wp)[i] = o;
        return;
    }
    const float* in; bf16* outp; int K, N, tb;
    if (b2 < 2081) { in = mlp_w1; outp = W1t; K = 1024; N = 4096; tb = b2 - 1057; }
    else           { in = mlp_w2; outp = W2t; K = 4096; N = 1024; tb = b2 - 2081; }
    int nx = N >> 6;
    int x0 = (tb % nx) * 64, y0 = (tb / nx) * 64;
    int tx = t & 15, ty = t >> 4;
    #pragma unroll
    for (int i = 0; i < 4; ++i) {
        float4 w = *(const float4*)(in + (size_t)(y0 + ty + i * 16) * N + x0 + tx * 4);
        tl[ty + i * 16][tx * 4 + 0] = w.x; tl[ty + i * 16][tx * 4 + 1] = w.y;
        tl[ty + i * 16][tx * 4 + 2] = w.z; tl[ty + i * 16][tx * 4 + 3] = w.w;
    }
    __syncthreads();
    #pragma unroll
    for (int i = 0; i < 4; ++i) {
        int nl = ty + i * 16;
        bf16x4 o = { (bf16)tl[tx * 4 + 0][nl], (bf16)tl[tx * 4 + 1][nl],
                     (bf16)tl[tx * 4 + 2][nl], (bf16)tl[tx * 4 + 3][nl] };
        *(bf16x4*)(outp + (size_t)(x0 + nl) * K + y0 + tx * 4) = o;
    }
}

// ---------------- rmsnorm2 (bf16 in, bf16 out) ----------------
__global__ __launch_bounds__(256) void rms2b_kernel(
    const bf16* __restrict__ x, const float* __restrict__ nw, bf16* __restrict__ y) {
    __shared__ float red[4];
    int t = threadIdx.x;
    size_t row = blockIdx.x;
    bf16x4 hv = ((const bf16x4*)(x + row * DD))[t];
    float x0 = (float)hv[0], x1 = (float)hv[1], x2 = (float)hv[2], x3 = (float)hv[3];
    float ss = x0*x0 + x1*x1 + x2*x2 + x3*x3;
    for (int m = 32; m; m >>= 1) ss += __shfl_xor(ss, m);
    if ((t & 63) == 0) red[t >> 6] = ss;
    __syncthreads();
    float tot = red[0] + red[1] + red[2] + red[3];
    float rinv = rsqrtf(tot * (1.0f / 1024.0f) + 1e-6f);
    float4 wv = ((const float4*)nw)[t];
    bf16x4 o = { (bf16)(x0 * rinv * wv.x), (bf16)(x1 * rinv * wv.y),
                 (bf16)(x2 * rinv * wv.z), (bf16)(x3 * rinv * wv.w) };
    ((bf16x4*)(y + row * DD))[t] = o;
}

// ---------------- qk projection + l2norm via MFMA, 32-row tiles, BK=128 -----
__global__ __launch_bounds__(256) void qk_kernel(
    const bf16* __restrict__ hn, const bf16* __restrict__ Ut,
    const float* __restrict__ pp, float* __restrict__ qa, float* __restrict__ kk) {
    __shared__ __attribute__((aligned(16))) bf16 As[32 * 128];
    __shared__ __attribute__((aligned(16))) bf16 Bs[32 * 128];
    int tid = threadIdx.x, lane = tid & 63, wid = tid >> 6;
    int quad = lane >> 4, l16 = lane & 15;
    int m0 = blockIdx.x * 32;
    int mt = wid >> 1, nt = wid & 1;
    const bf16* Ap[2]; const bf16* Bp[2]; int lo[2];
    #pragma unroll
    for (int j = 0; j < 2; ++j) {
        int s = j * 256 + tid;
        int row = s >> 4, cc = s & 15;
        int gc = cc ^ (row & 15);
        Ap[j] = hn + (size_t)(m0 + row) * DD + gc * 8;
        Bp[j] = Ut + (size_t)row * DD + gc * 8;
        lo[j] = s * 8;
    }
    floatx4 acc = {};
    for (int kt = 0; kt < 1024; kt += 128) {
        #pragma unroll
        for (int j = 0; j < 2; ++j) {
            g2l16(Ap[j] + kt, As + lo[j]);
            g2l16(Bp[j] + kt, Bs + lo[j]);
        }
        __syncthreads();
        #pragma unroll
        for (int ks = 0; ks < 4; ++ks) {
            int arow = mt * 16 + l16;
            int acc_ = (ks * 4 + quad) ^ (arow & 15);
            bf16x8 af = *(const bf16x8*)(As + arow * 128 + acc_ * 8);
            int brow = nt * 16 + l16;
            int bcc = (ks * 4 + quad) ^ (brow & 15);
            bf16x8 bfr = *(const bf16x8*)(Bs + brow * 128 + bcc * 8);
            acc = __builtin_amdgcn_mfma_f32_16x16x32_bf16(af, bfr, acc, 0, 0, 0);
        }
        __syncthreads();
    }
    float alf = pp[PP_ALPHA + l16];
    float s2[4];
    #pragma unroll
    for (int r = 0; r < 4; ++r) s2[r] = acc[r] * acc[r];
    #pragma unroll
    for (int m = 1; m <= 8; m <<= 1)
        #pragma unroll
        for (int r = 0; r < 4; ++r) s2[r] += __shfl_xor(s2[r], m);
    #pragma unroll
    for (int r = 0; r < 4; ++r) {
        size_t row = m0 + mt * 16 + quad * 4 + r;
        float den = fmaxf(sqrtf(s2[r]), 1e-8f);
        float nvl = acc[r] / den;
        if (nt == 0) qa[row * RR + l16] = nvl * alf;
        else         kk[row * RR + l16] = nvl;
    }
}

// ---------------- phase A: per-chunk KV increments ----------------
__global__ __launch_bounds__(256) void incr_kernel(
    const bf16* __restrict__ hn, const float* __restrict__ kk,
    const float* __restrict__ pp, float* __restrict__ Inc) {
    __shared__ __attribute__((aligned(16))) float wjr[64][16];
    int t = threadIdx.x;
    int bc = blockIdx.x;
    int d0 = blockIdx.y * 512 + t * 2;
    size_t row0 = (size_t)bc * 64;
    for (int idx = t; idx < 1024; idx += 256) {
        int j = idx >> 4, r = idx & 15;
        wjr[j][r] = kk[(row0 + j) * RR + r] * pp[PP_GP + r * 72 + (63 - j)];
    }
    __syncthreads();
    float acc0[16] = {}, acc1[16] = {};
    for (int j = 0; j < 64; ++j) {
        bf16x2 hv = *(const bf16x2*)(hn + (row0 + j) * DD + d0);
        float x0 = (float)hv[0], x1 = (float)hv[1];
        const float4* w4 = (const float4*)wjr[j];
        #pragma unroll
        for (int g = 0; g < 4; ++g) {
            float4 w = w4[g];
            acc0[g*4+0] += w.x * x0; acc0[g*4+1] += w.y * x0;
            acc0[g*4+2] += w.z * x0; acc0[g*4+3] += w.w * x0;
            acc1[g*4+0] += w.x * x1; acc1[g*4+1] += w.y * x1;
            acc1[g*4+2] += w.z * x1; acc1[g*4+3] += w.w * x1;
        }
    }
    float* outp = Inc + (size_t)bc * 16 * 1024 + d0;
    #pragma unroll
    for (int r = 0; r < 16; ++r) {
        float2 o = { acc0[r], acc1[r] };
        *(float2*)&outp[r * 1024] = o;
    }
}

// ---------------- phase B: sequential chunk-state scan (bf16 out) -----------
__global__ __launch_bounds__(256) void scan_kernel(
    const float* __restrict__ Inc, const float* __restrict__ pp,
    bf16* __restrict__ Sprevb) {
    int gid = blockIdx.x * 256 + threadIdx.x;
    int b = gid >> 14, rd = gid & 16383;
    int r = rd >> 10;
    float gd = pp[PP_GP + r * 72 + 64];
    float s = 0.0f;
    for (int c = 0; c < 16; ++c) {
        size_t idx = ((size_t)(b * 16 + c) << 14) + rd;
        Sprevb[idx] = (bf16)s;
        s = s * gd + Inc[idx];
    }
}

// ---------------- phase C via MFMA: M(64x96) @ X(96x1024-slice) -------------
#define XK 104
__global__ __launch_bounds__(256, 2) void phasec_kernel(
    const bf16* __restrict__ hn, const float* __restrict__ qa, const float* __restrict__ kk,
    const bf16* __restrict__ Sprevb, const float* __restrict__ pp,
    bf16* __restrict__ outpre) {
    __shared__ __attribute__((aligned(16))) bf16 Xt[128][XK];
    __shared__ __attribute__((aligned(16))) bf16 Mb[64][XK];
    __shared__ __attribute__((aligned(16))) float qa_s[64][16];
    __shared__ __attribute__((aligned(16))) float kk_s[64][16];
    __shared__ __attribute__((aligned(16))) float gpt[65][16];
    __shared__ float kks[4];
    int t = threadIdx.x;
    int bc = blockIdx.x;
    int c = bc & 15;
    size_t row0 = (size_t)bc * 64;
    for (int idx = t; idx < 1024; idx += 256) {
        int j = idx >> 4, r = idx & 15;
        qa_s[j][r] = qa[(row0 + j) * RR + r];
        kk_s[j][r] = kk[(row0 + j) * RR + r];
    }
    for (int idx = t; idx < 16 * 65; idx += 256) {
        int p = idx >> 4, r = idx & 15;
        gpt[p][r] = pp[PP_GP + r * 72 + p];
    }
    if (t < 4) kks[t] = pp[PP_KKER + t];
    __syncthreads();
    for (int idx = t; idx < 64 * 96; idx += 256) {
        int ii = idx / 96, jj = idx - ii * 96;
        float val = 0.0f;
        if (jj < 64) {
            if (jj <= ii) {
                const float4* qa4 = (const float4*)qa_s[ii];
                const float4* kk4 = (const float4*)kk_s[jj];
                const float4* gp4 = (const float4*)gpt[ii - jj];
                float s = 0.0f;
                #pragma unroll
                for (int x = 0; x < 4; ++x) {
                    float4 qv = qa4[x], kv = kk4[x], gv = gp4[x];
                    s += qv.x*kv.x*gv.x + qv.y*kv.y*gv.y + qv.z*kv.z*gv.z + qv.w*kv.w*gv.w;
                }
                val = s;
                if (ii - jj <= 3) val += kks[ii - jj];
            }
        } else if (jj < 80) {
            int r = jj - 64;
            val = qa_s[ii][r] * gpt[ii + 1][r];
        } else if (jj < 83) {
            int p = jj - 80;
            if (ii <= p) val = kks[ii + 3 - p];
        }
        Mb[ii][jj] = (bf16)val;
    }
    int lane = t & 63, w = t >> 6, quad = lane >> 4, l16 = lane & 15;
    for (int it = 0; it < 2; ++it) {
        int dt = blockIdx.y * 256 + it * 128;
        __syncthreads();
        for (int idx = t; idx < 64 * 32; idx += 256) {
            int j = idx >> 5, ch = idx & 31;
            bf16x4 hv = *(const bf16x4*)(hn + (row0 + j) * DD + dt + ch * 4);
            #pragma unroll
            for (int ee = 0; ee < 4; ++ee) {
                int e = (ee + t) & 3;
                Xt[ch * 4 + e][j] = hv[e];
            }
        }
        for (int idx = t; idx < 16 * 128; idx += 256) {
            int r = idx >> 7, dd = idx & 127;
            Xt[dd][64 + r] = Sprevb[((size_t)bc << 14) + r * 1024 + dt + dd];
        }
        for (int idx = t; idx < 128 * 16; idx += 256) {
            int dd = idx >> 4, p = idx & 15;
            bf16 val = (bf16)0.0f;
            if (p < 3 && c > 0) val = hn[(row0 - 3 + p) * DD + dt + dd];
            Xt[dd][80 + p] = val;
        }
        __syncthreads();
        floatx4 acc[8] = {};
        #pragma unroll
        for (int ks = 0; ks < 3; ++ks) {
            bf16x8 af = *(const bf16x8*)(&Mb[w * 16 + l16][ks * 32 + quad * 8]);
            #pragma unroll
            for (int tn = 0; tn < 8; ++tn) {
                bf16x8 bfr = *(const bf16x8*)(&Xt[tn * 16 + l16][ks * 32 + quad * 8]);
                acc[tn] = __builtin_amdgcn_mfma_f32_16x16x32_bf16(af, bfr, acc[tn], 0, 0, 0);
            }
        }
        #pragma unroll
        for (int tn = 0; tn < 8; ++tn) {
            #pragma unroll
            for (int r = 0; r < 4; ++r) {
                size_t ii = w * 16 + quad * 4 + r;
                outpre[(row0 + ii) * DD + dt + tn * 16 + l16] = (bf16)acc[tn][r];
            }
        }
    }
}

// ---------------- MFMA GEMM, templated, XOR-swizzled LDS, XCD cohorts -------
// EPI 0: outb = (bf16)(acc + bias + residf), paired bf16x2 stores [proj -> h2b]
// EPI 1: outb = (bf16)gelu(acc + bias), paired bf16x2 stores [mlp1 -> hidden]
// EPI 2: outf = acc + bias + (float)residb    [mlp2 -> d_out]
template <int EPI, int BK>
__global__ __launch_bounds__(256, 2) void gemm_bt_kernel(
    const bf16* __restrict__ A, const bf16* __restrict__ Bt,
    const float* __restrict__ bias, const float* __restrict__ residf,
    const bf16* __restrict__ residb, float* __restrict__ outf,
    bf16* __restrict__ outb, int K, int N) {
    constexpr int CH = BK / 8;
    constexpr int PT = 128 * CH / 256;
    __shared__ __attribute__((aligned(16))) bf16 As[128 * BK];
    __shared__ __attribute__((aligned(16))) bf16 Bs[128 * BK];
    int tid = threadIdx.x, lane = tid & 63, wid = tid >> 6;
    int quad = lane >> 4, l16 = lane & 15;
    int lb = blockIdx.y * gridDim.x + blockIdx.x;
    int xcd = lb & 7, q = lb >> 3;
    int m0 = (xcd * 8 + (q & 7)) * 128;
    int n0 = (q >> 3) * 128;
    int wm = (wid >> 1) * 64, wn = (wid & 1) * 64;
    const bf16* Ap[PT]; const bf16* Bp[PT]; int lo[PT];
    #pragma unroll
    for (int j = 0; j < PT; ++j) {
        int s = j * 256 + tid;
        int row = s / CH, cc = s % CH;
        int gc = cc ^ (row & (CH - 1));
        Ap[j] = A  + (size_t)(m0 + row) * K + gc * 8;
        Bp[j] = Bt + (size_t)(n0 + row) * K + gc * 8;
        lo[j] = s * 8;
    }
    floatx4 acc[4][4] = {};
    for (int kt = 0; kt < K; kt += BK) {
        #pragma unroll
        for (int j = 0; j < PT; ++j) {
            g2l16(Ap[j] + kt, As + lo[j]);
            g2l16(Bp[j] + kt, Bs + lo[j]);
        }
        __syncthreads();
        #pragma unroll
        for (int ks = 0; ks < BK / 32; ++ks) {
            bf16x8 af[4], bfr[4];
            #pragma unroll
            for (int tm = 0; tm < 4; ++tm) {
                int row = wm + tm * 16 + l16;
                int cc = (ks * 4 + quad) ^ (row & (CH - 1));
                af[tm] = *(const bf16x8*)(As + row * BK + cc * 8);
            }
            #pragma unroll
            for (int tn = 0; tn < 4; ++tn) {
                int row = wn + tn * 16 + l16;
                int cc = (ks * 4 + quad) ^ (row & (CH - 1));
                bfr[tn] = *(const bf16x8*)(Bs + row * BK + cc * 8);
            }
            #pragma unroll
            for (int tm = 0; tm < 4; ++tm)
                #pragma unroll
                for (int tn = 0; tn < 4; ++tn)
                    acc[tm][tn] = __builtin_amdgcn_mfma_f32_16x16x32_bf16(
                        af[tm], bfr[tn], acc[tm][tn], 0, 0, 0);
        }
        __syncthreads();
    }
    if (EPI == 2) {
        #pragma unroll
        for (int tn = 0; tn < 4; ++tn) {
            int gn = n0 + wn + tn * 16 + l16;
            float bs = bias[gn];
            #pragma unroll
            for (int tm = 0; tm < 4; ++tm) {
                #pragma unroll
                for (int r = 0; r < 4; ++r) {
                    size_t gm = (size_t)m0 + wm + tm * 16 + quad * 4 + r;
                    float v = acc[tm][tn][r] + bs;
                    v += (float)residb[gm * N + gn];
                    outf[gm * N + gn] = v;
                }
            }
        }
    } else {
        // bf16 output: pair adjacent cols via shfl, store bf16x2 from even lanes,
        // tn innermost so same-row 32B pieces are consecutive (L2 write-combine)
        float bs[4];
        #pragma unroll
        for (int tn = 0; tn < 4; ++tn) bs[tn] = bias[n0 + wn + tn * 16 + l16];
        #pragma unroll
        for (int tm = 0; tm < 4; ++tm) {
            #pragma unroll
            for (int r = 0; r < 4; ++r) {
                size_t gm = (size_t)m0 + wm + tm * 16 + quad * 4 + r;
                float vv[4];
                #pragma unroll
                for (int tn = 0; tn < 4; ++tn) {
                    float vx = acc[tm][tn][r] + bs[tn];
                    if (EPI == 0) vx += residf[gm * N + n0 + wn + tn * 16 + l16];
                    else          vx = gelu_f(vx);
                    vv[tn] = vx;
                }
                #pragma unroll
                for (int tn = 0; tn < 4; ++tn) {
                    float po = __shfl_xor(vv[tn], 1);
                    if ((l16 & 1) == 0) {
                        bf16x2 o = { (bf16)vv[tn], (bf16)po };
                        *(bf16x2*)(outb + gm * N + n0 + wn + tn * 16 + l16) = o;
                    }
                }
            }
        }
    }
}

// ---------------- launch ----------------
extern "C" void kernel_launch(void* const* d_in, const int* in_sizes, int n_in,
                              void* d_out, int out_size, void* d_ws, size_t ws_size,
                              hipStream_t stream) {
    const float* h           = (const float*)d_in[0];
    const float* u           = (const float*)d_in[1];
    const float* v           = (const float*)d_in[2];
    const float* decay_logit = (const float*)d_in[3];
    const float* alpha_logit = (const float*)d_in[4];
    const float* gate_logit  = (const float*)d_in[5];
    const float* kbase       = (const float*)d_in[6];
    const float* proj_w      = (const float*)d_in[7];
    const float* proj_b      = (const float*)d_in[8];
    const float* norm1_w     = (const float*)d_in[9];
    const float* norm2_w     = (const float*)d_in[10];
    const float* mlp_w1      = (const float*)d_in[11];
    const float* mlp_b1      = (const float*)d_in[12];
    const float* mlp_w2      = (const float*)d_in[13];
    const float* mlp_b2      = (const float*)d_in[14];
    float* out = (float*)d_out;

    char* wsb = (char*)d_ws;
    size_t off = 0;
    auto alloc = [&](size_t bytes) -> void* {
        void* p = wsb + off;
        off += (bytes + 255) & ~(size_t)255;
        return p;
    };
    float* pp     = (float*)alloc(PP_FLOATS * 4);
    bf16*  Ut     = (bf16*) alloc((size_t)32 * 1024 * 2);
    bf16*  hn     = (bf16*) alloc((size_t)8192 * 1024 * 2);
    float* qa     = (float*)alloc((size_t)8192 * 16 * 4);
    float* kk     = (float*)alloc((size_t)8192 * 16 * 4);
    float* Inc    = (float*)alloc((size_t)128 * 16 * 1024 * 4);
    bf16*  Sprevb = (bf16*) alloc((size_t)128 * 16 * 1024 * 2);
    bf16*  outpre = (bf16*) alloc((size_t)8192 * 1024 * 2);
    bf16*  h2b    = (bf16*) alloc((size_t)8192 * 1024 * 2);
    bf16*  hidden = (bf16*) alloc((size_t)8192 * 4096 * 2);
    bf16*  Wp     = (bf16*) alloc((size_t)1024 * 1024 * 2);
    bf16*  W1t    = (bf16*) alloc((size_t)4096 * 1024 * 2);
    bf16*  W2t    = (bf16*) alloc((size_t)1024 * 4096 * 2);
    bf16*  hn2 = hn;   // hn dead after phasec

    prep_kernel<<<8192 + 3105, 256, 0, stream>>>(
        h, norm1_w, decay_logit, alpha_logit, gate_logit, kbase,
        u, v, proj_w, mlp_w1, mlp_w2, pp, hn, Ut, Wp, W1t, W2t);
    qk_kernel<<<256, 256, 0, stream>>>(hn, Ut, pp, qa, kk);
    incr_kernel<<<dim3(128, 2), 256, 0, stream>>>(hn, kk, pp, Inc);
    scan_kernel<<<512, 256, 0, stream>>>(Inc, pp, Sprevb);
    phasec_kernel<<<dim3(128, 4), 256, 0, stream>>>(hn, qa, kk, Sprevb, pp, outpre);
    gemm_bt_kernel<0, 128><<<dim3(8, 64), 256, 0, stream>>>(
        outpre, Wp, proj_b, h, nullptr, nullptr, h2b, 1024, 1024);
    rms2b_kernel<<<8192, 256, 0, stream>>>(h2b, norm2_w, hn2);
    gemm_bt_kernel<1, 64><<<dim3(32, 64), 256, 0, stream>>>(
        hn2, W1t, mlp_b1, nullptr, nullptr, nullptr, hidden, 1024, 4096);
    gemm_bt_kernel<2, 128><<<dim3(8, 64), 256, 0, stream>>>(
        hidden, W2t, mlp_b2, nullptr, h2b, out, nullptr, 4096, 1024);
}